// Round 7
// baseline (403.581 us; speedup 1.0000x reference)
//
#include <hip/hip_runtime.h>
#include <hip/hip_bf16.h>
#include <math.h>
#include <stdint.h>

#define DDIM 512
#define QN   256
#define MT   128            // rows per block = 4 row-waves x 32
#define WAVES 8
#define NT   512
#define KNN  5
#define BK   64
#define NSTEP (DDIM / BK)   // 8
#define QTILE_B 32768       // 256 q-rows x 128 B (64 bf16), XOR-swizzled chunks
#define BIGF 3.0e38f

typedef __attribute__((ext_vector_type(8))) short bf16x8;
typedef __attribute__((ext_vector_type(4))) float f32x4;

#define SB0() __builtin_amdgcn_sched_barrier(0)

// async global->LDS, 16B per lane; LDS dest = uniform base + lane*16 (linear);
// swizzle achieved by pre-swizzling the per-lane GLOBAL source address.
__device__ __forceinline__ void gload16(const void* g, void* l) {
    __builtin_amdgcn_global_load_lds(
        (const __attribute__((address_space(1))) void*)g,
        (__attribute__((address_space(3))) void*)l, 16, 0, 0);
}

__device__ __forceinline__ bf16x8 pack8(float4 a, float4 b) {
    union { bf16x8 v; __hip_bfloat162 h[4]; } u;
    u.h[0] = __float22bfloat162_rn(make_float2(a.x, a.y));
    u.h[1] = __float22bfloat162_rn(make_float2(a.z, a.w));
    u.h[2] = __float22bfloat162_rn(make_float2(b.x, b.y));
    u.h[3] = __float22bfloat162_rn(make_float2(b.z, b.w));
    return u.v;
}
__device__ __forceinline__ float sq8(float4 a, float4 b, float s) {
    s = fmaf(a.x,a.x,s); s = fmaf(a.y,a.y,s); s = fmaf(a.z,a.z,s); s = fmaf(a.w,a.w,s);
    s = fmaf(b.x,b.x,s); s = fmaf(b.y,b.y,s); s = fmaf(b.z,b.z,s); s = fmaf(b.w,b.w,s);
    return s;
}

// Packed top-5 insert (idx in low 7 mantissa bits). Static indices only.
__device__ __forceinline__ void t5p_insert(float (&s)[KNN], float v) {
    if (v < s[4]) {
        s[4] = v;
        if (s[4] < s[3]) { float t = s[3]; s[3] = s[4]; s[4] = t; }
        if (s[3] < s[2]) { float t = s[2]; s[2] = s[3]; s[3] = t; }
        if (s[2] < s[1]) { float t = s[1]; s[1] = s[2]; s[2] = t; }
        if (s[1] < s[0]) { float t = s[0]; s[0] = s[1]; s[1] = t; }
    }
}
__device__ __forceinline__ void t5_insert(float (&s)[KNN], int (&ix)[KNN], float v, int vi) {
    if (v < s[4]) {
        s[4] = v; ix[4] = vi;
        if (s[4] < s[3]) { float t = s[3]; s[3] = s[4]; s[4] = t; int u = ix[3]; ix[3] = ix[4]; ix[4] = u; }
        if (s[3] < s[2]) { float t = s[2]; s[2] = s[3]; s[3] = t; int u = ix[2]; ix[2] = ix[3]; ix[3] = u; }
        if (s[2] < s[1]) { float t = s[1]; s[1] = s[2]; s[2] = t; int u = ix[1]; ix[1] = ix[2]; ix[2] = u; }
        if (s[1] < s[0]) { float t = s[0]; s[0] = s[1]; s[1] = t; int u = ix[0]; ix[0] = ix[1]; ix[1] = u; }
    }
}

// Phase 0: queries f32 -> bf16 (256 KB, L2-resident afterwards)
__global__ void conv_q(const float* __restrict__ emb, unsigned short* __restrict__ qbf) {
    int i = blockIdx.x * 256 + threadIdx.x;
    float4 v = ((const float4*)emb)[i];
    union { ushort4 u; __hip_bfloat162 h[2]; } o;
    o.h[0] = __float22bfloat162_rn(make_float2(v.x, v.y));
    o.h[1] = __float22bfloat162_rn(make_float2(v.z, v.w));
    ((ushort4*)qbf)[i] = o.u;
}

// Phase A: 128-row chunks. 8 waves = 4 row-waves x 2 q-waves; wave = 32 rows x
// 128 q (2 row-frags x 8 q-frags, each b-frag feeds 2 MFMAs). BK=64 q tile,
// XOR-swizzled, double-buffered, staged via global_load_lds with pre-swizzled
// source; counted vmcnt(8) barriers keep prefetch in flight.
__global__ __launch_bounds__(NT, 4) void knn_partial(
        const float* __restrict__ mem, const unsigned short* __restrict__ qbf,
        float* __restrict__ cand, int N) {
    __shared__ union {
        char  q[2][QTILE_B];            // 64 KB (K-loop)
        float mbuf[4][QN][KNN];         // 20 KB (epilogue)
    } sm;
    __shared__ float smsq[MT];

    const int tid  = threadIdx.x;
    const int lane = tid & 63;
    const int w    = tid >> 6;          // 0..7
    const int rw   = w & 3;             // row-wave
    const int qw   = w >> 2;            // q-wave (sibling waves share A rows; L1/L2 absorbs)
    const int l15  = lane & 15;
    const int lq   = lane >> 4;         // k-slice within 32-k half
    const int chunk = blockIdx.x;
    const int rbase = chunk * MT;

    // A rows for this wave's two row-frags
    int r0 = rbase + rw * 32 + l15;      if (r0 >= N) r0 = N - 1;
    int r1 = rbase + rw * 32 + 16 + l15; if (r1 >= N) r1 = N - 1;
    const char* pA0 = (const char*)(mem + (size_t)r0 * DDIM) + lq * 32;
    const char* pA1 = (const char*)(mem + (size_t)r1 * DDIM) + lq * 32;
    // per step s: half0 at +s*256 +{0,16}, half1 at +s*256 +{128,144}

    // staging: wave w stages q-rows [w*32, w*32+32) via 4 gload16; LDS linear,
    // source chunk pre-swizzled: c = (lane&7) ^ (lane>>3)
    const int srow = w * 32 + (lane >> 3);
    const int schunk = (lane & 7) ^ (lane >> 3);
    const char* qsrc = (const char*)qbf + (size_t)srow * 1024 + schunk * 16;
    const int ldst = w * 4096;          // + i*1024, uniform per wave-instr

    // LDS read offsets: q-row qr = qw*128 + qf*16 + l15; chunk c = 4h + lq;
    // byte = qr*128 + ((c ^ (qr&7))*16); qr&7 == l15&7 -> qf-independent base
    const int xr  = l15 & 7;
    const int rd0 = qw * 16384 + l15 * 128 + ((lq ^ xr) * 16);
    const int rd1 = qw * 16384 + l15 * 128 + (((4 + lq) ^ xr) * 16);

    f32x4 acc[8][2];
    const f32x4 z4 = {0.f, 0.f, 0.f, 0.f};
#pragma unroll
    for (int qf = 0; qf < 8; ++qf) { acc[qf][0] = z4; acc[qf][1] = z4; }
    float sq0 = 0.f, sq1 = 0.f;

    // prologue: stage(0) + A(0)
    gload16(qsrc,         sm.q[0] + ldst);
    gload16(qsrc + 8192,  sm.q[0] + ldst + 1024);
    gload16(qsrc + 16384, sm.q[0] + ldst + 2048);
    gload16(qsrc + 24576, sm.q[0] + ldst + 3072);
    float4 av[8];
    av[0] = *(const float4*)(pA0);        av[1] = *(const float4*)(pA0 + 16);
    av[4] = *(const float4*)(pA1);        av[5] = *(const float4*)(pA1 + 16);
    av[2] = *(const float4*)(pA0 + 128);  av[3] = *(const float4*)(pA0 + 144);
    av[6] = *(const float4*)(pA1 + 128);  av[7] = *(const float4*)(pA1 + 144);
    asm volatile("s_waitcnt vmcnt(8)" ::: "memory");   // stages done; A in flight
    __builtin_amdgcn_s_barrier();
    SB0();

    for (int s = 0; s < NSTEP; ++s) {
        const char* rp = sm.q[s & 1];
        const bool pre = (s + 1 < NSTEP);
        // --- half 0: convert, reissue A(s+1,h0), MFMA ---
        bf16x8 a00 = pack8(av[0], av[1]);
        bf16x8 a10 = pack8(av[4], av[5]);
        sq0 = sq8(av[0], av[1], sq0);
        sq1 = sq8(av[4], av[5], sq1);
        SB0();
        if (pre) {
            const char* qs = qsrc + (s + 1) * 128;
            char* db = sm.q[(s + 1) & 1] + ldst;
            gload16(qs,         db);
            gload16(qs + 8192,  db + 1024);
            gload16(qs + 16384, db + 2048);
            gload16(qs + 24576, db + 3072);
            SB0();
            const char* a0 = pA0 + (s + 1) * 256;
            const char* a1 = pA1 + (s + 1) * 256;
            av[0] = *(const float4*)(a0);      av[1] = *(const float4*)(a0 + 16);
            av[4] = *(const float4*)(a1);      av[5] = *(const float4*)(a1 + 16);
        }
        SB0();
#pragma unroll
        for (int qf = 0; qf < 8; ++qf) {
            bf16x8 b = *(const bf16x8*)(rp + rd0 + qf * 2048);
            acc[qf][0] = __builtin_amdgcn_mfma_f32_16x16x32_bf16(a00, b, acc[qf][0], 0, 0, 0);
            acc[qf][1] = __builtin_amdgcn_mfma_f32_16x16x32_bf16(a10, b, acc[qf][1], 0, 0, 0);
        }
        // --- half 1 ---
        bf16x8 a01 = pack8(av[2], av[3]);
        bf16x8 a11 = pack8(av[6], av[7]);
        sq0 = sq8(av[2], av[3], sq0);
        sq1 = sq8(av[6], av[7], sq1);
        SB0();
        if (pre) {
            const char* a0 = pA0 + (s + 1) * 256;
            const char* a1 = pA1 + (s + 1) * 256;
            av[2] = *(const float4*)(a0 + 128); av[3] = *(const float4*)(a0 + 144);
            av[6] = *(const float4*)(a1 + 128); av[7] = *(const float4*)(a1 + 144);
        }
        SB0();
#pragma unroll
        for (int qf = 0; qf < 8; ++qf) {
            bf16x8 b = *(const bf16x8*)(rp + rd1 + qf * 2048);
            acc[qf][0] = __builtin_amdgcn_mfma_f32_16x16x32_bf16(a01, b, acc[qf][0], 0, 0, 0);
            acc[qf][1] = __builtin_amdgcn_mfma_f32_16x16x32_bf16(a11, b, acc[qf][1], 0, 0, 0);
        }
        // drain LDS reads; stages complete (vmcnt<=8 leaves the 8 A-loads flying)
        asm volatile("s_waitcnt lgkmcnt(0)" ::: "memory");
        SB0();
        asm volatile("s_waitcnt vmcnt(8)" ::: "memory");
        __builtin_amdgcn_s_barrier();
        SB0();
    }

    // ||m||^2 per row: reduce k-slices across lq (shfl), publish via LDS
    sq0 += __shfl_xor(sq0, 16); sq0 += __shfl_xor(sq0, 32);
    sq1 += __shfl_xor(sq1, 16); sq1 += __shfl_xor(sq1, 32);
    if (lane < 16) {              // q-wave siblings write identical values
        smsq[rw * 32 + lane]      = sq0;
        smsq[rw * 32 + 16 + lane] = sq1;
    }
    __syncthreads();
    float rsq0[4], rsq1[4];
    *(float4*)rsq0 = *(const float4*)&smsq[rw * 32 + lq * 4];
    *(float4*)rsq1 = *(const float4*)&smsq[rw * 32 + 16 + lq * 4];

    // per q-frag: packed scores -> lane top5 -> shfl merge -> mbuf (aliases q)
#pragma unroll
    for (int qf = 0; qf < 8; ++qf) {
        float ts[KNN] = {BIGF, BIGF, BIGF, BIGF, BIGF};
#pragma unroll
        for (int e = 0; e < 4; ++e) {
            int rl0 = rw * 32 + lq * 4 + e;                 // row-frag 0
            if (rbase + rl0 < N) {
                float sc = fmaf(-2.f, acc[qf][0][e], rsq0[e]);
                t5p_insert(ts, __int_as_float((__float_as_int(sc) & ~127) | rl0));
            }
            int rl1 = rl0 + 16;                             // row-frag 1
            if (rbase + rl1 < N) {
                float sc = fmaf(-2.f, acc[qf][1][e], rsq1[e]);
                t5p_insert(ts, __int_as_float((__float_as_int(sc) & ~127) | rl1));
            }
        }
#pragma unroll
        for (int x = 16; x <= 32; x <<= 1) {
            float os[KNN];
#pragma unroll
            for (int c = 0; c < KNN; ++c) os[c] = __shfl_xor(ts[c], x);
#pragma unroll
            for (int c = 0; c < KNN; ++c) t5p_insert(ts, os[c]);
        }
        if (lane < 16) {
            int q = qw * 128 + qf * 16 + l15;
#pragma unroll
            for (int c = 0; c < KNN; ++c) sm.mbuf[rw][q][c] = ts[c];
        }
    }
    __syncthreads();
    if (tid < QN) {   // query tid: merge 4 row-waves, coalesced cand write
        float fsv[KNN] = {BIGF, BIGF, BIGF, BIGF, BIGF};
#pragma unroll
        for (int ww = 0; ww < 4; ++ww)
#pragma unroll
            for (int c = 0; c < KNN; ++c)
                t5p_insert(fsv, sm.mbuf[ww][tid][c]);
        float* dst = cand + ((size_t)chunk * QN + tid) * KNN;
#pragma unroll
        for (int c = 0; c < KNN; ++c) dst[c] = fsv[c];
    }
}

// Phase B: one wave per query: global top-5 over NC*5 packed candidates,
// gather rows, exact f32 distances (immune to bf16/packing jitter), sum.
__global__ void knn_merge_exact(const float* __restrict__ emb, const float* __restrict__ mem,
                                const float* __restrict__ cand, float* __restrict__ qsum,
                                int Q, int NC) {
    const int q = blockIdx.x;
    const int lane = threadIdx.x;  // 64
    float fs[KNN] = {BIGF, BIGF, BIGF, BIGF, BIGF};
    int   fi[KNN] = {0, 0, 0, 0, 0};
    for (int c = lane; c < NC; c += 64) {
        const float* p = cand + ((size_t)c * Q + q) * KNN;
#pragma unroll
        for (int k = 0; k < KNN; ++k) {
            float pk = p[k];
            int idx = c * MT + (__float_as_int(pk) & 127);
            t5_insert(fs, fi, pk, idx);
        }
    }
    __shared__ float2 ls[64][KNN];
    __shared__ int sel[KNN];
#pragma unroll
    for (int k = 0; k < KNN; ++k) ls[lane][k] = make_float2(fs[k], __int_as_float(fi[k]));
    __syncthreads();
    if (lane == 0) {
        float gs[KNN] = {BIGF, BIGF, BIGF, BIGF, BIGF};
        int   gi[KNN] = {0, 0, 0, 0, 0};
        for (int l = 0; l < 64; ++l)
#pragma unroll
            for (int k = 0; k < KNN; ++k)
                t5_insert(gs, gi, ls[l][k].x, __float_as_int(ls[l][k].y));
#pragma unroll
        for (int k = 0; k < KNN; ++k) sel[k] = gi[k];
    }
    __syncthreads();
    const float4* qp = (const float4*)(emb + (size_t)q * DDIM);
    float4 q0 = qp[lane * 2], q1 = qp[lane * 2 + 1];
    float ssum = 0.f;
    for (int k = 0; k < KNN; ++k) {
        const float4* mp = (const float4*)(mem + (size_t)sel[k] * DDIM);
        float4 m0 = mp[lane * 2], m1 = mp[lane * 2 + 1];
        float d0 = m0.x - q0.x, d1 = m0.y - q0.y, d2 = m0.z - q0.z, d3 = m0.w - q0.w;
        float d4 = m1.x - q1.x, d5 = m1.y - q1.y, d6 = m1.z - q1.z, d7 = m1.w - q1.w;
        float t = d0*d0 + d1*d1 + d2*d2 + d3*d3 + d4*d4 + d5*d5 + d6*d6 + d7*d7;
#pragma unroll
        for (int off = 32; off > 0; off >>= 1) t += __shfl_down(t, off);
        if (lane == 0) ssum += sqrtf(t);
    }
    if (lane == 0) qsum[q] = ssum;
}

__global__ void knn_reduce(const float* __restrict__ qsum, float* __restrict__ out, int Q) {
    const int lane = threadIdx.x;
    float v = 0.f;
    for (int i = lane; i < Q; i += 64) v += qsum[i];
#pragma unroll
    for (int off = 32; off > 0; off >>= 1) v += __shfl_down(v, off);
    if (lane == 0) out[0] = v / (float)(Q * KNN);
}

extern "C" void kernel_launch(void* const* d_in, const int* in_sizes, int n_in,
                              void* d_out, int out_size, void* d_ws, size_t ws_size,
                              hipStream_t stream) {
    (void)n_in; (void)out_size; (void)ws_size;
    const float* emb = (const float*)d_in[0];
    const float* mem = (const float*)d_in[1];
    const int Q  = in_sizes[0] / DDIM;       // 256
    const int N  = in_sizes[1] / DDIM;       // 200000
    const int NC = (N + MT - 1) / MT;        // 1563

    float*          cand = (float*)d_ws;                                         // NC*Q*5*4B ~ 8 MB
    float*          qsum = (float*)((char*)d_ws + (size_t)NC * Q * KNN * 4);     // 1 KB
    unsigned short* qbf  = (unsigned short*)((char*)d_ws + (size_t)NC * Q * KNN * 4 + 1024);

    conv_q<<<(Q * DDIM / 4 + 255) / 256, 256, 0, stream>>>(emb, qbf);
    knn_partial<<<NC, NT, 0, stream>>>(mem, qbf, cand, N);
    knn_merge_exact<<<Q, 64, 0, stream>>>(emb, mem, cand, qsum, Q, NC);
    knn_reduce<<<1, 64, 0, stream>>>(qsum, (float*)d_out, Q);
}

// Round 8
// 256.250 us; speedup vs baseline: 1.5750x; 1.5750x over previous
//
#include <hip/hip_runtime.h>
#include <hip/hip_bf16.h>
#include <math.h>
#include <stdint.h>

#define DDIM 512
#define QN   256
#define MT   128            // rows per block = 8 waves x 16 (single-owner, no dup)
#define WAVES 8
#define NT   512
#define KNN  5
#define BK   32
#define NSTEP (DDIM / BK)   // 16
#define QTILE_B 16384       // 256 q-rows x 64 B (32 bf16), XOR-swizzled 16B slots
#define BIGF 3.0e38f

typedef __attribute__((ext_vector_type(8))) short bf16x8;
typedef __attribute__((ext_vector_type(4))) float f32x4;

#define SB0() __builtin_amdgcn_sched_barrier(0)

// async global->LDS: LDS dest is WAVE-UNIFORM base (HW adds lane*16);
// per-lane GLOBAL source carries the swizzle (rule #21: linear dest +
// inverse-swizzled source + swizzled read = same involution).
__device__ __forceinline__ void gload16(const void* g, void* l) {
    __builtin_amdgcn_global_load_lds(
        (const __attribute__((address_space(1))) void*)g,
        (__attribute__((address_space(3))) void*)l, 16, 0, 0);
}

__device__ __forceinline__ bf16x8 pack8(float4 a, float4 b) {
    union { bf16x8 v; __hip_bfloat162 h[4]; } u;
    u.h[0] = __float22bfloat162_rn(make_float2(a.x, a.y));
    u.h[1] = __float22bfloat162_rn(make_float2(a.z, a.w));
    u.h[2] = __float22bfloat162_rn(make_float2(b.x, b.y));
    u.h[3] = __float22bfloat162_rn(make_float2(b.z, b.w));
    return u.v;
}
__device__ __forceinline__ float sq8(float4 a, float4 b, float s) {
    s = fmaf(a.x,a.x,s); s = fmaf(a.y,a.y,s); s = fmaf(a.z,a.z,s); s = fmaf(a.w,a.w,s);
    s = fmaf(b.x,b.x,s); s = fmaf(b.y,b.y,s); s = fmaf(b.z,b.z,s); s = fmaf(b.w,b.w,s);
    return s;
}

// Packed top-5 insert (idx in low 7 mantissa bits). Static indices only.
__device__ __forceinline__ void t5p_insert(float (&s)[KNN], float v) {
    if (v < s[4]) {
        s[4] = v;
        if (s[4] < s[3]) { float t = s[3]; s[3] = s[4]; s[4] = t; }
        if (s[3] < s[2]) { float t = s[2]; s[2] = s[3]; s[3] = t; }
        if (s[2] < s[1]) { float t = s[1]; s[1] = s[2]; s[2] = t; }
        if (s[1] < s[0]) { float t = s[0]; s[0] = s[1]; s[1] = t; }
    }
}
__device__ __forceinline__ void t5_insert(float (&s)[KNN], int (&ix)[KNN], float v, int vi) {
    if (v < s[4]) {
        s[4] = v; ix[4] = vi;
        if (s[4] < s[3]) { float t = s[3]; s[3] = s[4]; s[4] = t; int u = ix[3]; ix[3] = ix[4]; ix[4] = u; }
        if (s[3] < s[2]) { float t = s[2]; s[2] = s[3]; s[3] = t; int u = ix[2]; ix[2] = ix[3]; ix[3] = u; }
        if (s[2] < s[1]) { float t = s[1]; s[1] = s[2]; s[2] = t; int u = ix[1]; ix[1] = ix[2]; ix[2] = u; }
        if (s[1] < s[0]) { float t = s[0]; s[0] = s[1]; s[1] = t; int u = ix[0]; ix[0] = ix[1]; ix[1] = u; }
    }
}

// Phase 0: queries f32 -> bf16 (256 KB, L2-resident afterwards)
__global__ void conv_q(const float* __restrict__ emb, unsigned short* __restrict__ qbf) {
    int i = blockIdx.x * 256 + threadIdx.x;
    float4 v = ((const float4*)emb)[i];
    union { ushort4 u; __hip_bfloat162 h[2]; } o;
    o.h[0] = __float22bfloat162_rn(make_float2(v.x, v.y));
    o.h[1] = __float22bfloat162_rn(make_float2(v.z, v.w));
    ((ushort4*)qbf)[i] = o.u;
}

// Phase A: 128-row chunks; 8 waves x 16 rows (each mem byte read ONCE).
// Double-buffered [256][64B] swizzled q tile via gload_lds (pre-swizzled
// source); A prefetched at top-of-step; vmcnt(2)+raw barrier per step keeps
// A-loads in flight across the barrier.
__global__ __launch_bounds__(NT, 4) void knn_partial(
        const float* __restrict__ mem, const unsigned short* __restrict__ qbf,
        float* __restrict__ cand, int N) {
    __shared__ union {
        char  q[2][QTILE_B];            // 32 KB (K-loop)
        float mbuf[WAVES][QN][KNN];     // 40 KB (epilogue)
    } sm;
    __shared__ float smsq[MT];

    const int tid  = threadIdx.x;
    const int lane = tid & 63;
    const int w    = tid >> 6;          // 0..7
    const int l15  = lane & 15;
    const int lq   = lane >> 4;         // k-quarter 0..3
    const int chunk = blockIdx.x;
    const int rbase = chunk * MT;

    // A: wave w owns rows rbase + w*16 .. +15; lane covers 8 dims (lq*8)
    int gr = rbase + w * 16 + l15; if (gr >= N) gr = N - 1;
    const float* pA = mem + (size_t)gr * DDIM + lq * 8;

    // q staging: wave w stages q-rows [w*32, w*32+32) as 2 gload16/lane.
    // LDS linear: byte = w*2048 + i*1024 + lane*16 -> row = b>>6, slot = (b>>4)&3
    // source chunk = slot ^ (row&3)  (involution with the read swizzle)
    const int srow0 = w * 32 + (lane >> 2);
    const int schunk = (lane & 3) ^ ((lane >> 2) & 3);
    const char* qsrc0 = (const char*)qbf + (size_t)srow0 * 1024 + schunk * 16;
    const char* qsrc1 = qsrc0 + 16 * 1024;            // rows +16
    const int ldst = w * 2048;                        // wave-uniform LDS base

    // read: q-row qr = g*16 + l15, slot = lq ^ (l15&3); +g*1024 folds to imm
    const int rd = l15 * 64 + ((lq ^ (l15 & 3)) << 4);

    f32x4 acc[16];
    const f32x4 z4 = {0.f, 0.f, 0.f, 0.f};
#pragma unroll
    for (int g = 0; g < 16; ++g) acc[g] = z4;
    float sq = 0.f;

    // prologue: stage(0) + A(0)
    gload16(qsrc0, sm.q[0] + ldst);
    gload16(qsrc1, sm.q[0] + ldst + 1024);
    float4 av0 = *(const float4*)(pA);
    float4 av1 = *(const float4*)(pA + 4);
    SB0();
    asm volatile("s_waitcnt vmcnt(2)" ::: "memory");  // stage(0) done; A flying
    __builtin_amdgcn_s_barrier();
    SB0();

    for (int s = 0; s < NSTEP; ++s) {
        const char* rp = sm.q[s & 1];
        const bool pre = (s + 1 < NSTEP);
        float4 avn0, avn1;
        if (pre) {                       // issue next stage + next A at TOP
            char* db = sm.q[(s + 1) & 1] + ldst;
            gload16(qsrc0 + (s + 1) * 64, db);
            gload16(qsrc1 + (s + 1) * 64, db + 1024);
            avn0 = *(const float4*)(pA + (s + 1) * BK);
            avn1 = *(const float4*)(pA + (s + 1) * BK + 4);
        }
        bf16x8 a = pack8(av0, av1);
        sq = sq8(av0, av1, sq);
#pragma unroll
        for (int g = 0; g < 16; ++g) {
            bf16x8 b = *(const bf16x8*)(rp + rd + g * 1024);
            acc[g] = __builtin_amdgcn_mfma_f32_16x16x32_bf16(a, b, acc[g], 0, 0, 0);
        }
        if (pre) {
            SB0();                       // pin loads above the wait
            asm volatile("s_waitcnt vmcnt(2)" ::: "memory");  // stage done; A(s+1) stays in flight
            __builtin_amdgcn_s_barrier();
            SB0();
            av0 = avn0; av1 = avn1;
        }
    }

    // ||m||^2 per row (reduce k-quarters across lq)
    sq += __shfl_xor(sq, 16);
    sq += __shfl_xor(sq, 32);
    if (lane < 16) smsq[w * 16 + lane] = sq;
    __syncthreads();                     // also fences last q-buffer reads
    float rsqa[4];
#pragma unroll
    for (int e = 0; e < 4; ++e) rsqa[e] = smsq[w * 16 + lq * 4 + e];

    // per q-group: packed scores -> lane top5 -> shfl merge -> mbuf slice
#pragma unroll
    for (int g = 0; g < 16; ++g) {
        float ts[KNN] = {BIGF, BIGF, BIGF, BIGF, BIGF};
#pragma unroll
        for (int e = 0; e < 4; ++e) {
            int rl = w * 16 + lq * 4 + e;          // chunk-local row 0..127
            if (rbase + rl < N) {
                float sc = fmaf(-2.f, acc[g][e], rsqa[e]);
                t5p_insert(ts, __int_as_float((__float_as_int(sc) & ~127) | rl));
            }
        }
#pragma unroll
        for (int x = 16; x <= 32; x <<= 1) {
            float os[KNN];
#pragma unroll
            for (int c = 0; c < KNN; ++c) os[c] = __shfl_xor(ts[c], x);
#pragma unroll
            for (int c = 0; c < KNN; ++c) t5p_insert(ts, os[c]);
        }
        if (lane < 16) {
#pragma unroll
            for (int c = 0; c < KNN; ++c) sm.mbuf[w][g * 16 + lane][c] = ts[c];
        }
    }
    __syncthreads();
    if (tid < QN) {   // query tid: merge 8 waves, coalesced cand write
        float fsv[KNN] = {BIGF, BIGF, BIGF, BIGF, BIGF};
#pragma unroll
        for (int ww = 0; ww < WAVES; ++ww)
#pragma unroll
            for (int c = 0; c < KNN; ++c)
                t5p_insert(fsv, sm.mbuf[ww][tid][c]);
        float* dst = cand + ((size_t)chunk * QN + tid) * KNN;
#pragma unroll
        for (int c = 0; c < KNN; ++c) dst[c] = fsv[c];
    }
}

// Phase B: one wave per query: global top-5 over NC*5 packed candidates,
// gather rows, exact f32 distances (immune to bf16/packing jitter), sum.
__global__ void knn_merge_exact(const float* __restrict__ emb, const float* __restrict__ mem,
                                const float* __restrict__ cand, float* __restrict__ qsum,
                                int Q, int NC) {
    const int q = blockIdx.x;
    const int lane = threadIdx.x;  // 64
    float fs[KNN] = {BIGF, BIGF, BIGF, BIGF, BIGF};
    int   fi[KNN] = {0, 0, 0, 0, 0};
    for (int c = lane; c < NC; c += 64) {
        const float* p = cand + ((size_t)c * Q + q) * KNN;
#pragma unroll
        for (int k = 0; k < KNN; ++k) {
            float pk = p[k];
            int idx = c * MT + (__float_as_int(pk) & 127);
            t5_insert(fs, fi, pk, idx);
        }
    }
    __shared__ float2 ls[64][KNN];
    __shared__ int sel[KNN];
#pragma unroll
    for (int k = 0; k < KNN; ++k) ls[lane][k] = make_float2(fs[k], __int_as_float(fi[k]));
    __syncthreads();
    if (lane == 0) {
        float gs[KNN] = {BIGF, BIGF, BIGF, BIGF, BIGF};
        int   gi[KNN] = {0, 0, 0, 0, 0};
        for (int l = 0; l < 64; ++l)
#pragma unroll
            for (int k = 0; k < KNN; ++k)
                t5_insert(gs, gi, ls[l][k].x, __float_as_int(ls[l][k].y));
#pragma unroll
        for (int k = 0; k < KNN; ++k) sel[k] = gi[k];
    }
    __syncthreads();
    const float4* qp = (const float4*)(emb + (size_t)q * DDIM);
    float4 q0 = qp[lane * 2], q1 = qp[lane * 2 + 1];
    float ssum = 0.f;
    for (int k = 0; k < KNN; ++k) {
        const float4* mp = (const float4*)(mem + (size_t)sel[k] * DDIM);
        float4 m0 = mp[lane * 2], m1 = mp[lane * 2 + 1];
        float d0 = m0.x - q0.x, d1 = m0.y - q0.y, d2 = m0.z - q0.z, d3 = m0.w - q0.w;
        float d4 = m1.x - q1.x, d5 = m1.y - q1.y, d6 = m1.z - q1.z, d7 = m1.w - q1.w;
        float t = d0*d0 + d1*d1 + d2*d2 + d3*d3 + d4*d4 + d5*d5 + d6*d6 + d7*d7;
#pragma unroll
        for (int off = 32; off > 0; off >>= 1) t += __shfl_down(t, off);
        if (lane == 0) ssum += sqrtf(t);
    }
    if (lane == 0) qsum[q] = ssum;
}

__global__ void knn_reduce(const float* __restrict__ qsum, float* __restrict__ out, int Q) {
    const int lane = threadIdx.x;
    float v = 0.f;
    for (int i = lane; i < Q; i += 64) v += qsum[i];
#pragma unroll
    for (int off = 32; off > 0; off >>= 1) v += __shfl_down(v, off);
    if (lane == 0) out[0] = v / (float)(Q * KNN);
}

extern "C" void kernel_launch(void* const* d_in, const int* in_sizes, int n_in,
                              void* d_out, int out_size, void* d_ws, size_t ws_size,
                              hipStream_t stream) {
    (void)n_in; (void)out_size; (void)ws_size;
    const float* emb = (const float*)d_in[0];
    const float* mem = (const float*)d_in[1];
    const int Q  = in_sizes[0] / DDIM;       // 256
    const int N  = in_sizes[1] / DDIM;       // 200000
    const int NC = (N + MT - 1) / MT;        // 1563

    float*          cand = (float*)d_ws;                                         // NC*Q*5*4B ~ 8 MB
    float*          qsum = (float*)((char*)d_ws + (size_t)NC * Q * KNN * 4);     // 1 KB
    unsigned short* qbf  = (unsigned short*)((char*)d_ws + (size_t)NC * Q * KNN * 4 + 1024);

    conv_q<<<(Q * DDIM / 4 + 255) / 256, 256, 0, stream>>>(emb, qbf);
    knn_partial<<<NC, NT, 0, stream>>>(mem, qbf, cand, N);
    knn_merge_exact<<<Q, 64, 0, stream>>>(emb, mem, cand, qsum, Q, NC);
    knn_reduce<<<1, 64, 0, stream>>>(qsum, (float*)d_out, Q);
}